// Round 1
// baseline (15983.502 us; speedup 1.0000x reference)
//
#include <hip/hip_runtime.h>
#include <math.h>

#define NB 64    // batch
#define TT 512   // time steps
#define IN 128   // input dim
#define HD 512   // hidden dim

__device__ __forceinline__ float sigf(float x) { return 1.0f / (1.0f + expf(-x)); }

// ws layout (floats):
//   h0T : [2][HD][NB]  (layer0 h, transposed [k][b]; also layer1 input)
//   h2T : [2][HD][NB]  (layer1 h)
//   c0  : [HD][NB]
//   c2  : [HD][NB]
// total 6*HD*NB floats = 786432 bytes

__global__ __launch_bounds__(256) void lstm_step(
    const float* __restrict__ x,
    const float* __restrict__ Wih0, const float* __restrict__ Whh0,
    const float* __restrict__ bih0, const float* __restrict__ bhh0,
    const float* __restrict__ Wih1, const float* __restrict__ Whh1,
    const float* __restrict__ bih1, const float* __restrict__ bhh1,
    float* __restrict__ ws, int s)
{
    float* h0T = ws;                  // [2][HD][NB]
    float* h2T = ws + 2 * HD * NB;    // [2][HD][NB]
    float* c0  = ws + 4 * HD * NB;    // [HD][NB]
    float* c2  = ws + 5 * HD * NB;    // [HD][NB]

    const int tid  = threadIdx.x;
    const int b    = tid & 63;        // lane = batch
    const int w    = tid >> 6;        // wave 0..3
    const int uloc = w >> 1;          // local unit 0/1
    const int g0   = (w & 1) * 2;     // gates {0,1} or {2,3}
    const int uglob = blockIdx.x * 2 + uloc;
    int r0 = (g0 + 0) * HD + uglob;   // weight row = gate*HD + unit
    int r1 = (g0 + 1) * HD + uglob;
    // rows are wave-uniform; make it provable so weights go through s_load
    r0 = __builtin_amdgcn_readfirstlane(r0);
    r1 = __builtin_amdgcn_readfirstlane(r1);

    const int cur  = s & 1;
    const int prev = cur ^ 1;
    const float* __restrict__ h0prev = h0T + prev * HD * NB;  // h0_{s-1}
    const float* __restrict__ h2prev = h2T + cur  * HD * NB;  // h2_{s-2}

    float a0 = bih0[r0] + bhh0[r0];   // layer0 gates for rows r0,r1
    float a1 = bih0[r1] + bhh0[r1];
    float a2 = bih1[r0] + bhh1[r0];   // layer1 gates for rows r0,r1
    float a3 = bih1[r1] + bhh1[r1];

    // ---- layer0 input part: x_t @ Wih0^T  (K = 128) ----
    {
        const int sx = (s < TT) ? s : (TT - 1);  // clamp (s==TT result unused)
        const float4* __restrict__ wa = (const float4*)(Wih0 + (size_t)r0 * IN);
        const float4* __restrict__ wb = (const float4*)(Wih0 + (size_t)r1 * IN);
        const float4* __restrict__ xq = (const float4*)(x + ((size_t)b * TT + sx) * IN);
        #pragma unroll 8
        for (int kq = 0; kq < IN / 4; ++kq) {
            float4 xv = xq[kq];
            float4 qa = wa[kq], qb = wb[kq];
            a0 += xv.x * qa.x + xv.y * qa.y + xv.z * qa.z + xv.w * qa.w;
            a1 += xv.x * qb.x + xv.y * qb.y + xv.z * qb.z + xv.w * qb.w;
        }
    }
    // ---- fused pass over h0_{s-1}: layer0 recurrent + layer1 input ----
    {
        const float4* __restrict__ wa = (const float4*)(Whh0 + (size_t)r0 * HD);
        const float4* __restrict__ wb = (const float4*)(Whh0 + (size_t)r1 * HD);
        const float4* __restrict__ wc = (const float4*)(Wih1 + (size_t)r0 * HD);
        const float4* __restrict__ wd = (const float4*)(Wih1 + (size_t)r1 * HD);
        #pragma unroll 4
        for (int kq = 0; kq < HD / 4; ++kq) {
            const float* hp = h0prev + kq * 4 * NB + b;
            float h0v = hp[0], h1v = hp[NB], h2v = hp[2 * NB], h3v = hp[3 * NB];
            float4 qa = wa[kq], qb = wb[kq], qc = wc[kq], qd = wd[kq];
            a0 += h0v * qa.x + h1v * qa.y + h2v * qa.z + h3v * qa.w;
            a1 += h0v * qb.x + h1v * qb.y + h2v * qb.z + h3v * qb.w;
            a2 += h0v * qc.x + h1v * qc.y + h2v * qc.z + h3v * qc.w;
            a3 += h0v * qd.x + h1v * qd.y + h2v * qd.z + h3v * qd.w;
        }
    }
    // ---- layer1 recurrent: h2_{s-2} @ Whh1^T ----
    {
        const float4* __restrict__ wa = (const float4*)(Whh1 + (size_t)r0 * HD);
        const float4* __restrict__ wb = (const float4*)(Whh1 + (size_t)r1 * HD);
        #pragma unroll 4
        for (int kq = 0; kq < HD / 4; ++kq) {
            const float* hp = h2prev + kq * 4 * NB + b;
            float h0v = hp[0], h1v = hp[NB], h2v = hp[2 * NB], h3v = hp[3 * NB];
            float4 qa = wa[kq], qb = wb[kq];
            a2 += h0v * qa.x + h1v * qa.y + h2v * qa.z + h3v * qa.w;
            a3 += h0v * qb.x + h1v * qb.y + h2v * qb.z + h3v * qb.w;
        }
    }

    // ---- gate exchange + state update ----
    __shared__ float gl[2][2][4][NB];
    gl[0][uloc][g0 + 0][b] = a0;
    gl[0][uloc][g0 + 1][b] = a1;
    gl[1][uloc][g0 + 0][b] = a2;
    gl[1][uloc][g0 + 1][b] = a3;
    __syncthreads();

    const int layer = tid >> 7;
    const int u2    = (tid >> 6) & 1;
    const int ug    = blockIdx.x * 2 + u2;
    if (layer == 0) {
        if (s < TT) {
            float gi = gl[0][u2][0][b], gf = gl[0][u2][1][b];
            float gc = gl[0][u2][2][b], go = gl[0][u2][3][b];
            float iv = sigf(gi), fv = sigf(gf), cv = tanhf(gc), ov = sigf(go);
            float cp = c0[ug * NB + b];
            float cn = fv * cp + iv * cv;
            c0[ug * NB + b] = cn;
            h0T[cur * HD * NB + ug * NB + b] = ov * tanhf(cn);
        }
    } else {
        if (s >= 1) {
            float gi = gl[1][u2][0][b], gf = gl[1][u2][1][b];
            float gc = gl[1][u2][2][b], go = gl[1][u2][3][b];
            float iv = sigf(gi), fv = sigf(gf), cv = tanhf(gc), ov = sigf(go);
            float cp = c2[ug * NB + b];
            float cn = fv * cp + iv * cv;
            c2[ug * NB + b] = cn;
            h2T[prev * HD * NB + ug * NB + b] = ov * tanhf(cn);  // h2_{s-1}
        }
    }
}

__global__ __launch_bounds__(64) void fc_kernel(
    const float* __restrict__ ws, const float* __restrict__ fcW,
    const float* __restrict__ fcb, float* __restrict__ out)
{
    // last h2 (t = TT-1) lives in h2T[(TT-1)&1] = h2T[1]
    const float* __restrict__ h2last = ws + 2 * HD * NB + ((TT - 1) & 1) * HD * NB;
    const int o = blockIdx.x;    // 0..23
    const int b = threadIdx.x;   // 0..63
    float acc = fcb[o];
    const float* __restrict__ wr = fcW + (size_t)o * HD;
    #pragma unroll 8
    for (int k = 0; k < HD; ++k)
        acc += h2last[k * NB + b] * wr[k];
    out[b * 24 + o] = acc;
}

extern "C" void kernel_launch(void* const* d_in, const int* in_sizes, int n_in,
                              void* d_out, int out_size, void* d_ws, size_t ws_size,
                              hipStream_t stream)
{
    const float* x    = (const float*)d_in[0];
    const float* Wih0 = (const float*)d_in[1];
    const float* Whh0 = (const float*)d_in[2];
    const float* bih0 = (const float*)d_in[3];
    const float* bhh0 = (const float*)d_in[4];
    const float* Wih1 = (const float*)d_in[5];
    const float* Whh1 = (const float*)d_in[6];
    const float* bih1 = (const float*)d_in[7];
    const float* bhh1 = (const float*)d_in[8];
    const float* fcW  = (const float*)d_in[9];
    const float* fcb  = (const float*)d_in[10];
    float* ws = (float*)d_ws;

    // zero h0T/h2T/c0/c2 every call (deterministic; graph-capturable)
    hipMemsetAsync(d_ws, 0, (size_t)6 * HD * NB * sizeof(float), stream);

    // pipelined scan: step s runs layer0 step s and layer1 step s-1
    for (int s = 0; s <= TT; ++s)
        lstm_step<<<dim3(256), dim3(256), 0, stream>>>(
            x, Wih0, Whh0, bih0, bhh0, Wih1, Whh1, bih1, bhh1, ws, s);

    fc_kernel<<<dim3(24), dim3(64), 0, stream>>>(ws, fcW, fcb, (float*)d_out);
}